// Round 4
// baseline (133.159 us; speedup 1.0000x reference)
//
#include <hip/hip_runtime.h>
#include <math.h>

#define N_NODES 1024
#define N_EVAL 131072
#define NUM_POLES 8
#define PI_D 3.14159265358979323846

// ============================================================================
// V5: wave-resident node registers + v_readlane broadcast.
//
// Post-mortems V1-V4: every variant stalls ~80% because the hot loop issues
// only ~4 VALU ops per operand-delivery event, and the delivery path (LDS
// reads in V1, s_load/K$ in V2/V3, ds_bpermute in V4) is shared + lockstep-
// correlated across waves, so TLP never composes. V4's register design was
// additionally defeated by the compiler (VGPR_Count=32 < the 48 needed ->
// node arrays were rematerialized/spilled, not resident).
//
// V5 removes the delivery path from every pipe except the VALU itself:
//  - Each wave holds 512 node triples (n, w, w*v) in 24 VGPRs/lane: lane l
//    owns nodes base+8l .. base+8l+7. Loaded once in the prologue, then
//    pinned with asm volatile("":"+v"(..)) so the compiler CANNOT turn them
//    back into loads (V4's failure).
//  - Hot loop: owner lane ow = 0..63 (runtime SGPR), slot k unrolled. Per
//    node: 3x v_readlane (VGPR -> SGPR broadcast, VALU pipe, no lgkmcnt /
//    LDS banks / latency) + per point {v_sub, v_rcp, 2x v_fma} with the
//    SGPR as the one scalar operand (1-SGPR-per-VALU rule respected).
//    88 inst/iter, 64 iters, zero memory ops. 4 independent fma chains +
//    independent rcps; 16 rcps/iter on the trans pipe overlap the main
//    VALU issue.
//  - Block = 128 thr = 2 waves (nodes 0-511 / 512-1023) x 128 points
//    (2/lane); grid = 1024 = 4 blocks/CU = 2 waves/SIMD. 2KB LDS reduce,
//    divide, rare exact-hit NaN fixup (reference: exact-hit column reduces
//    to sum(hit w*v)/sum(hit w)).
//
// setup_kernel: closed-form barycentric weights (fp64, once). For Chebyshev
// pts of the 2nd kind, 1/prod_{i!=j}(x_j-x_i) = (-1)^j*delta_j*2^(n-1)/n;
// uniform positive scalings cancel in num/den, so
// w_j = (-1)^j * delta_j * prod_m((x_j-pr_m)^2 + pi_m^2).
// ============================================================================

__global__ __launch_bounds__(256) void setup_kernel(
    const float* __restrict__ values,
    const float* __restrict__ poles_real,
    const float* __restrict__ poles_imag,
    float* __restrict__ ws) {
    const int j = blockIdx.x * 256 + threadIdx.x;
    const double nd = cos(PI_D * (double)j / (double)(N_NODES - 1));
    double prod = (j == 0 || j == N_NODES - 1) ? 0.5 : 1.0;
#pragma unroll
    for (int m = 0; m < NUM_POLES; ++m) {
        const double dr = nd - (double)poles_real[m];
        const double di = (double)poles_imag[m];
        prod *= dr * dr + di * di;
    }
    if (j & 1) prod = -prod;
    ws[j]        = (float)nd;
    ws[j + 1024] = (float)prod;
    ws[j + 2048] = (float)(prod * (double)values[j]);
}

__global__ __launch_bounds__(128) void eval_readlane_kernel(
    const float* __restrict__ x_eval,
    const float* __restrict__ ws,
    float* __restrict__ out) {
    __shared__ float2 s_red[2][128];

    const int t = threadIdx.x;
    const int lane = t & 63;
    const int wid  = t >> 6;              // 0 or 1
    const int pbase = blockIdx.x * 128;
    const int nb = wid * 512;             // this wave's node base

    // ---- prologue: 8 triples/lane into named registers (2KB/wave/array) ----
    float n0, n1, n2, n3, n4, n5, n6, n7;
    float w0, w1, w2, w3, w4, w5, w6, w7;
    float v0, v1, v2, v3, v4, v5, v6, v7;
    {
        const float4* np = (const float4*)(ws + nb)        + lane * 2;
        const float4* wp = (const float4*)(ws + 1024 + nb) + lane * 2;
        const float4* vp = (const float4*)(ws + 2048 + nb) + lane * 2;
        const float4 na = np[0], nbq = np[1];
        const float4 wa = wp[0], wb  = wp[1];
        const float4 va = vp[0], vb  = vp[1];
        n0 = na.x;  n1 = na.y;  n2 = na.z;  n3 = na.w;
        n4 = nbq.x; n5 = nbq.y; n6 = nbq.z; n7 = nbq.w;
        w0 = wa.x;  w1 = wa.y;  w2 = wa.z;  w3 = wa.w;
        w4 = wb.x;  w5 = wb.y;  w6 = wb.z;  w7 = wb.w;
        v0 = va.x;  v1 = va.y;  v2 = va.z;  v3 = va.w;
        v4 = vb.x;  v5 = vb.y;  v6 = vb.z;  v7 = vb.w;
    }
    // Pin as opaque register values: forbids rematerialization as loads
    // (V4's failure mode) and guarantees VGPR residency.
    asm volatile("" : "+v"(n0), "+v"(n1), "+v"(n2), "+v"(n3),
                      "+v"(n4), "+v"(n5), "+v"(n6), "+v"(n7));
    asm volatile("" : "+v"(w0), "+v"(w1), "+v"(w2), "+v"(w3),
                      "+v"(w4), "+v"(w5), "+v"(w6), "+v"(w7));
    asm volatile("" : "+v"(v0), "+v"(v1), "+v"(v2), "+v"(v3),
                      "+v"(v4), "+v"(v5), "+v"(v6), "+v"(v7));

    const float x0 = x_eval[pbase + lane];
    const float x1 = x_eval[pbase + 64 + lane];

    float a0 = 0.0f, b0 = 0.0f, a1 = 0.0f, b1 = 0.0f;

#define NODE(NK, WK, VK)                                                     \
    {                                                                        \
        const float sn = __int_as_float(                                     \
            __builtin_amdgcn_readlane(__float_as_int(NK), ow));              \
        const float sw = __int_as_float(                                     \
            __builtin_amdgcn_readlane(__float_as_int(WK), ow));              \
        const float sv = __int_as_float(                                     \
            __builtin_amdgcn_readlane(__float_as_int(VK), ow));              \
        const float d0 = x0 - sn;                                            \
        const float d1 = x1 - sn;                                            \
        const float r0 = __builtin_amdgcn_rcpf(d0);                          \
        const float r1 = __builtin_amdgcn_rcpf(d1);                          \
        a0 = fmaf(sv, r0, a0); b0 = fmaf(sw, r0, b0);                        \
        a1 = fmaf(sv, r1, a1); b1 = fmaf(sw, r1, b1);                        \
    }

    // 64 owner-lane iterations; zero memory/LDS ops inside.
#pragma unroll 2
    for (int ow = 0; ow < 64; ++ow) {
        NODE(n0, w0, v0) NODE(n1, w1, v1) NODE(n2, w2, v2) NODE(n3, w3, v3)
        NODE(n4, w4, v4) NODE(n5, w5, v5) NODE(n6, w6, v6) NODE(n7, w7, v7)
    }
#undef NODE

    s_red[wid][lane]      = make_float2(a0, b0);
    s_red[wid][lane + 64] = make_float2(a1, b1);
    __syncthreads();

    // ---- combine the two wave-halves, divide, rare exact-hit fixup ----
    if (t < 128) {
        const float2 p0 = s_red[0][t];
        const float2 p1 = s_red[1][t];
        float res = (p0.x + p1.x) / (p0.y + p1.y);
        if (__builtin_expect(__builtin_isnan(res), 0)) {
            const float xv = x_eval[pbase + t];
            float hn = 0.0f, hd = 0.0f;
            for (int jj = 0; jj < N_NODES; ++jj) {
                if (ws[jj] == xv) { hn += ws[2048 + jj]; hd += ws[1024 + jj]; }
            }
            res = hn / hd;
        }
        out[pbase + t] = res;
    }
}

// ============================================================================
// Fallback (verified round-0 kernel) if the harness workspace is too small.
// ============================================================================
__global__ __launch_bounds__(512, 4) void eval_kernel_fused(
    const float* __restrict__ x_eval,
    const float* __restrict__ values,
    const float* __restrict__ poles_real,
    const float* __restrict__ poles_imag,
    float* __restrict__ out) {
    __shared__ __align__(16) float s_n[N_NODES];
    __shared__ __align__(16) float s_w[N_NODES];
    __shared__ __align__(16) float s_v[N_NODES];
    __shared__ float2 s_r[8][256];

    const int t = threadIdx.x;

#pragma unroll
    for (int h = 0; h < 2; ++h) {
        const int j = t + h * 512;
        const double nd = cos(PI_D * (double)j / (double)(N_NODES - 1));
        double prod = (j == 0 || j == N_NODES - 1) ? 0.5 : 1.0;
#pragma unroll
        for (int m = 0; m < NUM_POLES; ++m) {
            const double dr = nd - (double)poles_real[m];
            const double di = (double)poles_imag[m];
            prod *= dr * dr + di * di;
        }
        if (j & 1) prod = -prod;
        s_n[j] = (float)nd;
        s_w[j] = (float)prod;
        s_v[j] = (float)(prod * (double)values[j]);
    }
    __syncthreads();

    const int lane = t & 63;
    const int wid  = t >> 6;
    const int pbase = blockIdx.x * 256;
    const float x0 = x_eval[pbase + lane];
    const float x1 = x_eval[pbase + 64 + lane];
    const float x2 = x_eval[pbase + 128 + lane];
    const float x3 = x_eval[pbase + 192 + lane];

    const float4* n4 = (const float4*)s_n + wid * 32;
    const float4* w4 = (const float4*)s_w + wid * 32;
    const float4* v4 = (const float4*)s_v + wid * 32;

    float a0 = 0.0f, b0 = 0.0f, a1 = 0.0f, b1 = 0.0f;
    float a2 = 0.0f, b2 = 0.0f, a3 = 0.0f, b3 = 0.0f;

#define NODE(C)                                                            \
    {                                                                      \
        const float d0 = x0 - an.C;                                        \
        const float d1 = x1 - an.C;                                        \
        const float d2 = x2 - an.C;                                        \
        const float d3 = x3 - an.C;                                        \
        const float r0 = __builtin_amdgcn_rcpf(d0);                        \
        const float r1 = __builtin_amdgcn_rcpf(d1);                        \
        const float r2 = __builtin_amdgcn_rcpf(d2);                        \
        const float r3 = __builtin_amdgcn_rcpf(d3);                        \
        a0 = fmaf(av.C, r0, a0); b0 = fmaf(aw.C, r0, b0);                  \
        a1 = fmaf(av.C, r1, a1); b1 = fmaf(aw.C, r1, b1);                  \
        a2 = fmaf(av.C, r2, a2); b2 = fmaf(aw.C, r2, b2);                  \
        a3 = fmaf(av.C, r3, a3); b3 = fmaf(aw.C, r3, b3);                  \
    }

#pragma unroll 4
    for (int q = 0; q < 32; ++q) {
        const float4 an = n4[q];
        const float4 aw = w4[q];
        const float4 av = v4[q];
        NODE(x) NODE(y) NODE(z) NODE(w)
    }
#undef NODE

    s_r[wid][lane]       = make_float2(a0, b0);
    s_r[wid][lane + 64]  = make_float2(a1, b1);
    s_r[wid][lane + 128] = make_float2(a2, b2);
    s_r[wid][lane + 192] = make_float2(a3, b3);
    __syncthreads();

    if (t < 256) {
        float nn = 0.0f, dd = 0.0f;
#pragma unroll
        for (int w = 0; w < 8; ++w) {
            const float2 pr = s_r[w][t];
            nn += pr.x;
            dd += pr.y;
        }
        float res = nn / dd;
        if (__builtin_expect(__builtin_isnan(res), 0)) {
            const float x = x_eval[pbase + t];
            float hn = 0.0f, hd = 0.0f;
            for (int j = 0; j < N_NODES; ++j) {
                if (s_n[j] == x) { hn += s_v[j]; hd += s_w[j]; }
            }
            res = hn / hd;
        }
        out[pbase + t] = res;
    }
}

extern "C" void kernel_launch(void* const* d_in, const int* in_sizes, int n_in,
                              void* d_out, int out_size, void* d_ws, size_t ws_size,
                              hipStream_t stream) {
    const float* x_eval     = (const float*)d_in[0];
    const float* values     = (const float*)d_in[1];
    const float* poles_real = (const float*)d_in[2];
    const float* poles_imag = (const float*)d_in[3];
    float* out = (float*)d_out;

    if (ws_size >= 3 * N_NODES * sizeof(float)) {
        float* ws = (float*)d_ws;
        setup_kernel<<<N_NODES / 256, 256, 0, stream>>>(values, poles_real,
                                                        poles_imag, ws);
        eval_readlane_kernel<<<N_EVAL / 128, 128, 0, stream>>>(x_eval, ws, out);
    } else {
        eval_kernel_fused<<<N_EVAL / 256, 512, 0, stream>>>(
            x_eval, values, poles_real, poles_imag, out);
    }
}